// Round 2
// baseline (447.134 us; speedup 1.0000x reference)
//
#include <hip/hip_runtime.h>
#include <math.h>

#define SEQ_LEN   2048
#define STATE_LEN 1024
#define N_POI     10000
#define EPS_VAL   1e-6f

// One block per output row (1024 blocks), 256 threads, 8 columns/thread.
// Gather row cur[b] of the distance matrix at columns his[j], energies = 1/d
// (or EPS where d==0), then numerically-stable row softmax entirely in
// registers + two small block reductions.
__global__ __launch_bounds__(256) void attn_loc_kernel(
    const int*   __restrict__ his,
    const int*   __restrict__ cur,
    const float* __restrict__ dist,
    float*       __restrict__ out)
{
    const int row = blockIdx.x;          // 0..STATE_LEN-1
    const int tid = threadIdx.x;         // 0..255

    const float* __restrict__ base = dist + (long long)cur[row] * N_POI;
    float* __restrict__ orow = out + (size_t)row * SEQ_LEN;

    float e[8];
    float lmax = -INFINITY;
    #pragma unroll
    for (int k = 0; k < 8; ++k) {
        const int j = tid + k * 256;           // coalesced his read
        const float d = base[his[j]];          // gathered (uncoalesced) read
        const float en = (d != 0.0f) ? (1.0f / d) : EPS_VAL;
        e[k] = en;
        lmax = fmaxf(lmax, en);
    }

    // ---- block max reduction (wave64 shuffle + 4-slot LDS) ----
    #pragma unroll
    for (int off = 32; off >= 1; off >>= 1)
        lmax = fmaxf(lmax, __shfl_xor(lmax, off, 64));

    __shared__ float smax[4];
    __shared__ float ssum[4];
    const int wave = tid >> 6;
    if ((tid & 63) == 0) smax[wave] = lmax;
    __syncthreads();
    const float m = fmaxf(fmaxf(smax[0], smax[1]), fmaxf(smax[2], smax[3]));

    // ---- exp + block sum reduction ----
    float lsum = 0.0f;
    #pragma unroll
    for (int k = 0; k < 8; ++k) {
        e[k] = expf(e[k] - m);
        lsum += e[k];
    }
    #pragma unroll
    for (int off = 32; off >= 1; off >>= 1)
        lsum += __shfl_xor(lsum, off, 64);
    if ((tid & 63) == 0) ssum[wave] = lsum;
    __syncthreads();
    const float s = ssum[0] + ssum[1] + ssum[2] + ssum[3];
    const float inv = 1.0f / s;

    // ---- normalize + coalesced store ----
    #pragma unroll
    for (int k = 0; k < 8; ++k)
        orow[tid + k * 256] = e[k] * inv;
}

extern "C" void kernel_launch(void* const* d_in, const int* in_sizes, int n_in,
                              void* d_out, int out_size, void* d_ws, size_t ws_size,
                              hipStream_t stream)
{
    const int*   his  = (const int*)d_in[0];    // (2048,)
    const int*   cur  = (const int*)d_in[1];    // (1024,)
    const float* dist = (const float*)d_in[2];  // (10000, 10000)
    float*       out  = (float*)d_out;          // (1024, 2048)

    attn_loc_kernel<<<STATE_LEN, 256, 0, stream>>>(his, cur, dist, out);
}

// Round 5
// 443.679 us; speedup vs baseline: 1.0078x; 1.0078x over previous
//
#include <hip/hip_runtime.h>
#include <math.h>

#define SEQ_LEN   2048
#define STATE_LEN 1024
#define N_POI     10000
#define EPS_VAL   1e-6f

// One block per output row (1024 blocks), 256 threads.
// Stage the full 40 KB distance-matrix row into LDS with coalesced float4
// loads, then gather the 2048 his[] columns from LDS, energies = 1/d
// (EPS where d==0), then in-register row softmax (max -> exp/sum -> norm).
__global__ __launch_bounds__(256) void attn_loc_kernel(
    const int*   __restrict__ his,
    const int*   __restrict__ cur,
    const float* __restrict__ dist,
    float*       __restrict__ out)
{
    __shared__ float srow[N_POI];            // 40000 B
    __shared__ float smax[4];
    __shared__ float ssum[4];

    const int row = blockIdx.x;              // 0..STATE_LEN-1
    const int tid = threadIdx.x;             // 0..255

    const float* __restrict__ base = dist + (long long)cur[row] * N_POI;
    float* __restrict__ orow = out + (size_t)row * SEQ_LEN;

    // ---- coalesced staging: 10000 floats = 2500 float4 ----
    {
        const float4* __restrict__ src4 = (const float4*)base;
        float4* dst4 = (float4*)srow;
        #pragma unroll
        for (int i = 0; i < 9; ++i)                    // 9*256 = 2304
            dst4[tid + i * 256] = src4[tid + i * 256];
        const int i9 = tid + 9 * 256;                  // tail: 2304..2499
        if (i9 < N_POI / 4) dst4[i9] = src4[i9];
    }

    // his indices for my 8 columns (coalesced) — overlap with staging
    int idx[8];
    #pragma unroll
    for (int k = 0; k < 8; ++k)
        idx[k] = his[tid + k * 256];

    __syncthreads();

    // ---- gather from LDS + energies + local max ----
    float e[8];
    float lmax = -INFINITY;
    #pragma unroll
    for (int k = 0; k < 8; ++k) {
        const float d = srow[idx[k]];
        const float en = (d != 0.0f) ? (1.0f / d) : EPS_VAL;
        e[k] = en;
        lmax = fmaxf(lmax, en);
    }

    // ---- block max reduction (wave64 shuffle + 4-slot LDS) ----
    #pragma unroll
    for (int off = 32; off >= 1; off >>= 1)
        lmax = fmaxf(lmax, __shfl_xor(lmax, off, 64));
    const int wave = tid >> 6;
    if ((tid & 63) == 0) smax[wave] = lmax;
    __syncthreads();
    const float m = fmaxf(fmaxf(smax[0], smax[1]), fmaxf(smax[2], smax[3]));

    // ---- exp + block sum reduction ----
    float lsum = 0.0f;
    #pragma unroll
    for (int k = 0; k < 8; ++k) {
        e[k] = expf(e[k] - m);
        lsum += e[k];
    }
    #pragma unroll
    for (int off = 32; off >= 1; off >>= 1)
        lsum += __shfl_xor(lsum, off, 64);
    if ((tid & 63) == 0) ssum[wave] = lsum;
    __syncthreads();
    const float s = ssum[0] + ssum[1] + ssum[2] + ssum[3];
    const float inv = 1.0f / s;

    // ---- normalize + coalesced store ----
    #pragma unroll
    for (int k = 0; k < 8; ++k)
        orow[tid + k * 256] = e[k] * inv;
}

extern "C" void kernel_launch(void* const* d_in, const int* in_sizes, int n_in,
                              void* d_out, int out_size, void* d_ws, size_t ws_size,
                              hipStream_t stream)
{
    const int*   his  = (const int*)d_in[0];    // (2048,)
    const int*   cur  = (const int*)d_in[1];    // (1024,)
    const float* dist = (const float*)d_in[2];  // (10000, 10000)
    float*       out  = (float*)d_out;          // (1024, 2048)

    attn_loc_kernel<<<STATE_LEN, 256, 0, stream>>>(his, cur, dist, out);
}

// Round 6
// 441.366 us; speedup vs baseline: 1.0131x; 1.0052x over previous
//
#include <hip/hip_runtime.h>
#include <math.h>

#define SEQ_LEN   2048
#define STATE_LEN 1024
#define N_POI     10000
#define EPS_VAL   1e-6f

// One block per output row (1024 blocks), 512 threads (8 waves).
// 40 KB LDS row stage -> 4 blocks/CU (LDS-limited) x 8 waves = 32 waves/CU
// = 100% occupancy (vs 50% with 256 threads), for staging latency hiding.
__global__ __launch_bounds__(512) void attn_loc_kernel(
    const int*   __restrict__ his,
    const int*   __restrict__ cur,
    const float* __restrict__ dist,
    float*       __restrict__ out)
{
    __shared__ float srow[N_POI];            // 40000 B
    __shared__ float smax[8];
    __shared__ float ssum[8];

    const int row = blockIdx.x;              // 0..STATE_LEN-1
    const int tid = threadIdx.x;             // 0..511

    const float* __restrict__ base = dist + (long long)cur[row] * N_POI;
    float* __restrict__ orow = out + (size_t)row * SEQ_LEN;

    // ---- coalesced staging: 10000 floats = 2500 float4 ----
    {
        const float4* __restrict__ src4 = (const float4*)base;
        float4* dst4 = (float4*)srow;
        #pragma unroll
        for (int i = 0; i < 4; ++i)                    // 4*512 = 2048
            dst4[tid + i * 512] = src4[tid + i * 512];
        const int i4 = tid + 4 * 512;                  // tail: 2048..2499
        if (i4 < N_POI / 4) dst4[i4] = src4[i4];
    }

    // his indices for my 4 columns (coalesced) — overlaps with staging
    int idx[4];
    #pragma unroll
    for (int k = 0; k < 4; ++k)
        idx[k] = his[tid + k * 512];

    __syncthreads();

    // ---- gather from LDS + energies + local max ----
    float e[4];
    float lmax = -INFINITY;
    #pragma unroll
    for (int k = 0; k < 4; ++k) {
        const float d = srow[idx[k]];
        const float en = (d != 0.0f) ? (1.0f / d) : EPS_VAL;
        e[k] = en;
        lmax = fmaxf(lmax, en);
    }

    // ---- block max reduction (wave64 shuffle + 8-slot LDS) ----
    #pragma unroll
    for (int off = 32; off >= 1; off >>= 1)
        lmax = fmaxf(lmax, __shfl_xor(lmax, off, 64));
    const int wave = tid >> 6;
    if ((tid & 63) == 0) smax[wave] = lmax;
    __syncthreads();
    float m = smax[0];
    #pragma unroll
    for (int w = 1; w < 8; ++w) m = fmaxf(m, smax[w]);

    // ---- exp + block sum reduction ----
    float lsum = 0.0f;
    #pragma unroll
    for (int k = 0; k < 4; ++k) {
        e[k] = __expf(e[k] - m);
        lsum += e[k];
    }
    #pragma unroll
    for (int off = 32; off >= 1; off >>= 1)
        lsum += __shfl_xor(lsum, off, 64);
    if ((tid & 63) == 0) ssum[wave] = lsum;
    __syncthreads();
    float s = ssum[0];
    #pragma unroll
    for (int w = 1; w < 8; ++w) s += ssum[w];
    const float inv = 1.0f / s;

    // ---- normalize + coalesced store ----
    #pragma unroll
    for (int k = 0; k < 4; ++k)
        orow[tid + k * 512] = e[k] * inv;
}

extern "C" void kernel_launch(void* const* d_in, const int* in_sizes, int n_in,
                              void* d_out, int out_size, void* d_ws, size_t ws_size,
                              hipStream_t stream)
{
    const int*   his  = (const int*)d_in[0];    // (2048,)
    const int*   cur  = (const int*)d_in[1];    // (1024,)
    const float* dist = (const float*)d_in[2];  // (10000, 10000)
    float*       out  = (float*)d_out;          // (1024, 2048)

    attn_loc_kernel<<<STATE_LEN, 512, 0, stream>>>(his, cur, dist, out);
}